// Round 14
// baseline (32.963 us; speedup 1.0000x reference)
//
#include <hip/hip_runtime.h>

#define NOUT 10
#define SIG_DIM 584   // 8 + 64 + 512

typedef float float8v __attribute__((ext_vector_type(8)));

// PARALLEL-IN-TIME closed form (r12-verified identity), minimal step body:
//   cp_t = X[t]-X[0];  dx_t = X[t+1]-X[t]
//   gg_t = dx_j*(cp_i + 0.5*dx_i)   (= dS2)   S2f = sum gg
//   hh_t = dx_j*(dx_i/6 + 0.5*cp_i)
//   A[k] = sum_t [(gg-hh)*X[t+1][k] + hh*X[t][k]]
//        = sum_t w_t*X[t][k] + gmh_last*X[t0+32][k],  w_t = hh_t + gmh_{t-1}
//   S3[ijk] = S2f[ij]*X127[k] - A[ijk];  S1 = X127-X0.
// Block = 1 batch, 4 waves = 4 independent 32-step chunks, additive combine.
// Rows X[t][k]: SGPR s_load_dwordx8 (uniform ptr) -- no VALU, no VGPR cost;
// safe now because the loop has NO ds_read (r8's lgkmcnt drain trap): columns
// are per-lane global_load_dword (8-lane cacheline broadcast, imm offsets).
// Per-step ~17 VALU, ~35 VGPR -> 8 waves/SIMD (r12 was VGPR-capped at 4).
__global__ __launch_bounds__(256) void sig_linear_kernel(
    const float* __restrict__ X, const float* __restrict__ W,
    const float* __restrict__ bias, float* __restrict__ out)
{
    __shared__ float s_s2[4][64];
    __shared__ float s_part[4][16];

    const int tid = threadIdx.x;
    const int w = tid >> 6, l = tid & 63, i = l >> 3, j = l & 7;
    const int b = blockIdx.x;
    const int t0 = w * 32;
    const float* Xb = X + (size_t)b * 1024;
    const float* Xu = X + (size_t)__builtin_amdgcn_readfirstlane(b) * 1024;

    // Per-lane column pointers: x[t0+s][i] = ci[s*8] (imm offsets when s const).
    const float* ci = Xb + t0 * 8 + i;
    const float* cj = Xb + t0 * 8 + j;
    const float x0i = Xb[i], x0j = Xb[j];

    float A[8];
#pragma unroll
    for (int k = 0; k < 8; ++k) A[k] = 0.f;
    float S2f = 0.f, gp = 0.f;          // gp = gmh_{t-1}
    float xci = ci[0], xcj = cj[0];
    const int rowN = (w == 3) ? 31 : 32;   // clamped local index of row t0+32
                                           // (w=3: dx_127=0 -> exact)

#pragma unroll
    for (int s = 0; s < 32; ++s) {
        const int sn = (s < 31) ? (s + 1) * 8 : rowN * 8;
        const float xni = ci[sn];                              // global dword
        const float xnj = cj[sn];                              // global dword
        const float8v rr = *reinterpret_cast<const float8v*>(Xu + (t0 + s) * 8); // s_load x8
        const float dxi = xni - xci;
        const float dxj = xnj - xcj;
        const float cpi = xci - x0i;
        const float gg = dxj * fmaf(0.5f, dxi, cpi);
        const float hh = dxj * fmaf(1.0f / 6.0f, dxi, 0.5f * cpi);
        const float wt = hh + gp;
        gp = gg - hh;
        S2f += gg;
#pragma unroll
        for (int k = 0; k < 8; ++k) A[k] = fmaf(wt, rr[k], A[k]);
        xci = xni;
        xcj = xnj;
    }
    {   // boundary term: A += gmh_last * X[t0+rowN]  (w=3: gp==0 exactly)
        const float8v rn = *reinterpret_cast<const float8v*>(Xu + (t0 + rowN) * 8);
#pragma unroll
        for (int k = 0; k < 8; ++k) A[k] = fmaf(gp, rn[k], A[k]);
    }

    // Additive combine of S2f across chunks (exact).
    s_s2[w][l] = S2f;
    __syncthreads();
    const float S2T = s_s2[0][l] + s_s2[1][l] + s_s2[2][l] + s_s2[3][l];

    // Epilogue (r12-verified): out[o] = sum_l [S2T*(W3.X127 + W2) - W3.A] + W1.S1 + bias
    // Each wave contributes -W3.A_w; wave 0 adds the S2T/S1 terms once.
    const float s1jv = Xb[1016 + j] - x0j;
    const float4 x7a = *reinterpret_cast<const float4*>(Xb + 1016);
    const float4 x7b = *reinterpret_cast<const float4*>(Xb + 1020);
#pragma unroll
    for (int o = 0; o < NOUT; ++o) {
        const float* wrow = W + o * SIG_DIM;
        const float4 w0 = *reinterpret_cast<const float4*>(wrow + 72 + l * 8);
        const float4 w1 = *reinterpret_cast<const float4*>(wrow + 72 + l * 8 + 4);
        float dA = w0.x * A[0];
        dA = fmaf(w0.y, A[1], dA); dA = fmaf(w0.z, A[2], dA);
        dA = fmaf(w0.w, A[3], dA); dA = fmaf(w1.x, A[4], dA);
        dA = fmaf(w1.y, A[5], dA); dA = fmaf(w1.z, A[6], dA);
        dA = fmaf(w1.w, A[7], dA);
        float part = -dA;
        if (w == 0) {
            float e = w0.x * x7a.x;
            e = fmaf(w0.y, x7a.y, e); e = fmaf(w0.z, x7a.z, e);
            e = fmaf(w0.w, x7a.w, e); e = fmaf(w1.x, x7b.x, e);
            e = fmaf(w1.y, x7b.y, e); e = fmaf(w1.z, x7b.z, e);
            e = fmaf(w1.w, x7b.w, e);
            part = fmaf(S2T, e + wrow[8 + l], part);
            if (i == 0) part = fmaf(s1jv, wrow[j], part);   // S1 contribution
        }
#pragma unroll
        for (int off = 32; off > 0; off >>= 1) part += __shfl_xor(part, off);
        if (l == o) s_part[w][o] = part;
    }
    __syncthreads();
    if (tid < NOUT)
        out[b * NOUT + tid] = s_part[0][tid] + s_part[1][tid] +
                              s_part[2][tid] + s_part[3][tid] + bias[tid];
}

extern "C" void kernel_launch(void* const* d_in, const int* in_sizes, int n_in,
                              void* d_out, int out_size, void* d_ws, size_t ws_size,
                              hipStream_t stream) {
    const float* X = (const float*)d_in[0];     // (2048, 128, 8)
    const float* W = (const float*)d_in[1];     // (10, 584)
    const float* bias = (const float*)d_in[2];  // (10,)
    float* out = (float*)d_out;                 // (2048, 10)
    sig_linear_kernel<<<dim3(2048), dim3(256), 0, stream>>>(X, W, bias, out);
}

// Round 15
// 24.258 us; speedup vs baseline: 1.3588x; 1.3588x over previous
//
#include <hip/hip_runtime.h>

#define NOUT 10
#define SIG_DIM 584   // 8 + 64 + 512
#define TPAD 132      // padded T-stride: (c*TPAD)%32 = 4c -> conflict-free cols

__device__ __forceinline__ float rdlane(float x, int lane) {
    return __int_as_float(__builtin_amdgcn_readlane(__float_as_int(x), lane));
}

// r5 kernel (best measured: 21.5 us) with ROLLED loops -- icache A/B test.
// r5's fully-unrolled 127-step body is ~26 KB of instructions (~L1 icache
// size); at 2 waves/SIMD instruction-fetch misses are unhideable and explain
// r5's 89%-stall signature (406 cy/step wall vs 46 cy issue). This version:
// 4 sequential sections x (#pragma unroll 1 loop over 8 groups of 4 steps),
// body ~100 instr (~4 KB total), readlane lane index = runtime SGPR
// (wave-uniform loop counter -- v_readlane allows SGPR lane select).
// Math, LDS layout, grid identical to r5. s1j via closed form (exact).
__global__ __launch_bounds__(256) void sig_linear_kernel(
    const float* __restrict__ X, const float* __restrict__ W,
    const float* __restrict__ bias, float* __restrict__ out)
{
    __shared__ float s_dxT[4][8 * TPAD];   // per-wave transposed dX (16.9 KB)

    const int tid = threadIdx.x;
    const int w = tid >> 6;
    const int l = tid & 63;
    const int i = l >> 3;
    const int j = l & 7;
    const int b = blockIdx.x * 4 + w;

    const float* Xb = X + (size_t)b * 1024;
    float* dxT = &s_dxT[w][0];
    const int cb = (l & 1) * 4;            // this lane's 4-col segment
    const int rl = l >> 1;                 // row within 32-row section

    // Prepass (r5-proven): dX rows q*32+rl -> regs dA..dD (readlane source:
    // lane 2s = row s cols 0-3, lane 2s+1 = cols 4-7) + transposed LDS
    // columns. Row 127 zeroed. Global loads lane-coalesced.
    float4 dA, dB, dC, dD;
#define PREP(DQ, QQ)                                                          \
    {                                                                         \
        const int r = (QQ) * 32 + rl;                                         \
        const float* xr = Xb + r * 8 + cb;                                    \
        const float4 a  = *reinterpret_cast<const float4*>(xr);               \
        const float4 c4 = *reinterpret_cast<const float4*>(xr + (r < 127 ? 8 : 0)); \
        DQ.x = (r < 127) ? c4.x - a.x : 0.f;                                  \
        DQ.y = (r < 127) ? c4.y - a.y : 0.f;                                  \
        DQ.z = (r < 127) ? c4.z - a.z : 0.f;                                  \
        DQ.w = (r < 127) ? c4.w - a.w : 0.f;                                  \
        dxT[(cb + 0) * TPAD + r] = DQ.x;                                      \
        dxT[(cb + 1) * TPAD + r] = DQ.y;                                      \
        dxT[(cb + 2) * TPAD + r] = DQ.z;                                      \
        dxT[(cb + 3) * TPAD + r] = DQ.w;                                      \
    }
    PREP(dA, 0) PREP(dB, 1) PREP(dC, 2) PREP(dD, 3)
#undef PREP
    __syncthreads();   // cross-lane LDS reads below need a real barrier

    float s3[8];
#pragma unroll
    for (int k = 0; k < 8; ++k) s3[k] = 0.f;
    float s2 = 0.f, s1i = 0.f;

    const float* icol = dxT + i * TPAD;    // conflict-free: banks 4c+t
    const float* jcol = dxT + j * TPAD;

    // One step; LB is a runtime (wave-uniform) readlane base.
#define STEP(DQ, LB, DXI, DXJ)                                                \
    {                                                                         \
        const float k0 = rdlane(DQ.x, (LB));                                  \
        const float k1 = rdlane(DQ.y, (LB));                                  \
        const float k2 = rdlane(DQ.z, (LB));                                  \
        const float k3 = rdlane(DQ.w, (LB));                                  \
        const float k4 = rdlane(DQ.x, (LB) + 1);                              \
        const float k5 = rdlane(DQ.y, (LB) + 1);                              \
        const float k6 = rdlane(DQ.z, (LB) + 1);                              \
        const float k7 = rdlane(DQ.w, (LB) + 1);                              \
        const float cc = (DXI) * (DXJ);                                       \
        const float uu = s1i * (DXJ);                                         \
        const float f  = fmaf(0.5f, uu, fmaf(1.0f / 6.0f, cc, s2));           \
        s3[0] = fmaf(f, k0, s3[0]);                                           \
        s3[1] = fmaf(f, k1, s3[1]);                                           \
        s3[2] = fmaf(f, k2, s3[2]);                                           \
        s3[3] = fmaf(f, k3, s3[3]);                                           \
        s3[4] = fmaf(f, k4, s3[4]);                                           \
        s3[5] = fmaf(f, k5, s3[5]);                                           \
        s3[6] = fmaf(f, k6, s3[6]);                                           \
        s3[7] = fmaf(f, k7, s3[7]);                                           \
        s2 = fmaf(0.5f, cc, s2 + uu);                                         \
        s1i += (DXI);                                                         \
    }

    // One 32-row section: ROLLED loop over 8 groups of 4 steps.
#define SECTION(DQ, QQ)                                                       \
    _Pragma("unroll 1")                                                       \
    for (int g = 0; g < 8; ++g) {                                             \
        const float4 ic = *reinterpret_cast<const float4*>(icol + (QQ) * 32 + g * 4); \
        const float4 jc = *reinterpret_cast<const float4*>(jcol + (QQ) * 32 + g * 4); \
        const int lb = g * 8;                                                 \
        STEP(DQ, lb + 0, ic.x, jc.x)                                          \
        STEP(DQ, lb + 2, ic.y, jc.y)                                          \
        STEP(DQ, lb + 4, ic.z, jc.z)                                          \
        STEP(DQ, lb + 6, ic.w, jc.w)                                          \
    }
    SECTION(dA, 0)
    SECTION(dB, 1)
    SECTION(dC, 2)
    SECTION(dD, 3)
#undef SECTION
#undef STEP

    // s1j closed form (telescoping, exact): X[127][j] - X[0][j].
    const float s1j = Xb[127 * 8 + j] - Xb[j];

    // Epilogue (r5-proven), ROLLED over o.
    // sig layout: [0..7]=S1, [8+l]=S2[i][j], [72+l*8+k]=S3[i][j][k]
#pragma unroll 1
    for (int o = 0; o < NOUT; ++o) {
        const float* wrow = W + o * SIG_DIM;
        float part = s2 * wrow[8 + l];
        const float4 w0 = *reinterpret_cast<const float4*>(wrow + 72 + l * 8);
        const float4 w1 = *reinterpret_cast<const float4*>(wrow + 72 + l * 8 + 4);
        part = fmaf(s3[0], w0.x, part); part = fmaf(s3[1], w0.y, part);
        part = fmaf(s3[2], w0.z, part); part = fmaf(s3[3], w0.w, part);
        part = fmaf(s3[4], w1.x, part); part = fmaf(s3[5], w1.y, part);
        part = fmaf(s3[6], w1.z, part); part = fmaf(s3[7], w1.w, part);
        if (i == 0) part = fmaf(s1j, wrow[j], part);   // S1 contribution
#pragma unroll
        for (int off = 32; off > 0; off >>= 1) part += __shfl_xor(part, off);
        if (l == 0) out[b * NOUT + o] = part + bias[o];
    }
}

extern "C" void kernel_launch(void* const* d_in, const int* in_sizes, int n_in,
                              void* d_out, int out_size, void* d_ws, size_t ws_size,
                              hipStream_t stream) {
    const float* X = (const float*)d_in[0];     // (2048, 128, 8)
    const float* W = (const float*)d_in[1];     // (10, 584)
    const float* bias = (const float*)d_in[2];  // (10,)
    float* out = (float*)d_out;                 // (2048, 10)
    sig_linear_kernel<<<dim3(512), dim3(256), 0, stream>>>(X, W, bias, out);
}